// Round 2
// baseline (10173.838 us; speedup 1.0000x reference)
//
#include <hip/hip_runtime.h>
#include <hip/hip_cooperative_groups.h>

namespace cg = cooperative_groups;

#define HID    1024
#define DVID   4096
#define DWORD  512
#define XLEN   (HID + DWORD)
#define NVOCAB 32000
#define NSTEP  39          // MAX_LEN - 1
#define NT     256
#define MAXNB  2048        // 8 blocks/CU x 256 CU
#define NEG_BIG (-3.402823466e38f)

__device__ __forceinline__ float fast_sigmoid(float x) { return 1.f / (1.f + __expf(-x)); }
__device__ __forceinline__ float fast_tanh(float x)    { return 1.f - 2.f / (__expf(2.f * x) + 1.f); }

__device__ __forceinline__ float wave_reduce(float v) {
#pragma unroll
    for (int o = 32; o; o >>= 1) v += __shfl_xor(v, o, 64);
    return v;
}

__device__ __forceinline__ void smax_comb(float& M, float& S, float m2, float s2) {
    float nm = fmaxf(M, m2);
    S = S * __expf(M - nm) + s2 * __expf(m2 - nm);
    M = nm;
}

// one wave: dot(w_row[0:len), x[0:len)); len multiple of 256; result on all lanes
__device__ __forceinline__ float row_dot(const float* __restrict__ w, const float* x, int len, int lane) {
    float acc = 0.f;
    for (int q = lane * 4; q < len; q += 256) {
        float4 wv = *(const float4*)(w + q);
        float4 xv = *(const float4*)(x + q);
        acc = fmaf(wv.x, xv.x, acc);
        acc = fmaf(wv.y, xv.y, acc);
        acc = fmaf(wv.z, xv.z, acc);
        acc = fmaf(wv.w, xv.w, acc);
    }
    return wave_reduce(acc);
}

// bf16 weight row (len = HID), fp32 x
__device__ __forceinline__ float row_dot_bf16(const unsigned short* __restrict__ w, const float* x, int lane) {
    float acc = 0.f;
#pragma unroll
    for (int q = lane * 8; q < HID; q += 512) {
        uint4  u  = *(const uint4*)(w + q);
        float4 x0 = *(const float4*)(x + q);
        float4 x1 = *(const float4*)(x + q + 4);
        acc = fmaf(__uint_as_float(u.x << 16),          x0.x, acc);
        acc = fmaf(__uint_as_float(u.x & 0xffff0000u),  x0.y, acc);
        acc = fmaf(__uint_as_float(u.y << 16),          x0.z, acc);
        acc = fmaf(__uint_as_float(u.y & 0xffff0000u),  x0.w, acc);
        acc = fmaf(__uint_as_float(u.z << 16),          x1.x, acc);
        acc = fmaf(__uint_as_float(u.z & 0xffff0000u),  x1.y, acc);
        acc = fmaf(__uint_as_float(u.w << 16),          x1.z, acc);
        acc = fmaf(__uint_as_float(u.w & 0xffff0000u),  x1.w, acc);
    }
    return wave_reduce(acc);
}

__device__ __forceinline__ void lstm_update1(const float* G, float* c, float* h, int tid) {
    for (int j = tid; j < HID; j += NT) {
        float gi = G[j], gf = G[j + HID], gg = G[j + 2 * HID], go = G[j + 3 * HID];
        float cn = fast_sigmoid(gf) * c[j] + fast_sigmoid(gi) * fast_tanh(gg);
        c[j] = cn;
        h[j] = fast_sigmoid(go) * fast_tanh(cn);
    }
}

__device__ __forceinline__ void lstm_update2(const float* Ga, const float* Gb, float* c, float* h, int tid) {
    for (int j = tid; j < HID; j += NT) {
        float gi = Ga[j] + Gb[j];
        float gf = Ga[j + HID] + Gb[j + HID];
        float gg = Ga[j + 2 * HID] + Gb[j + 2 * HID];
        float go = Ga[j + 3 * HID] + Gb[j + 3 * HID];
        float cn = fast_sigmoid(gf) * c[j] + fast_sigmoid(gi) * fast_tanh(gg);
        c[j] = cn;
        h[j] = fast_sigmoid(go) * fast_tanh(cn);
    }
}

// all threads of the block call; returns max + log(sumexp) combined over PM/PS[0:nbl)
__device__ float block_soft_off(const float* PM, const float* PS, int nbl,
                                int tid, int lane, int wib, float* sRm, float* sRs) {
    float M = NEG_BIG, S = 0.f;
    for (int i = tid; i < nbl; i += NT) smax_comb(M, S, PM[i], PS[i]);
#pragma unroll
    for (int o = 32; o; o >>= 1) {
        float m2 = __shfl_xor(M, o, 64), s2 = __shfl_xor(S, o, 64);
        smax_comb(M, S, m2, s2);
    }
    if (lane == 0) { sRm[wib] = M; sRs[wib] = S; }
    __syncthreads();
    M = sRm[0]; S = sRs[0];
    for (int w = 1; w < NT / 64; ++w) smax_comb(M, S, sRm[w], sRs[w]);
    return M + __logf(S);
}

__device__ __forceinline__ unsigned short f2bf(float f) {
    unsigned int u = __float_as_uint(f);
    u += 0x7fffu + ((u >> 16) & 1u);   // RNE
    return (unsigned short)(u >> 16);
}

__global__ void cvt_kernel(const float* __restrict__ w, unsigned short* __restrict__ o, int n) {
    int i = (blockIdx.x * 256 + threadIdx.x) * 4;
    if (i >= n) return;
    float4 v = *(const float4*)(w + i);
    ushort4 r;
    r.x = f2bf(v.x); r.y = f2bf(v.y); r.z = f2bf(v.z); r.w = f2bf(v.w);
    *(ushort4*)(o + i) = r;
}

__global__ __launch_bounds__(NT, 8) void seq2seq_kernel(
    const float* __restrict__ vid,
    const float* __restrict__ w_ih1, const float* __restrict__ w_hh1,
    const float* __restrict__ b_ih1, const float* __restrict__ b_hh1,
    const float* __restrict__ w_ih2, const float* __restrict__ w_hh2,
    const float* __restrict__ b_ih2, const float* __restrict__ b_hh2,
    const float* __restrict__ emb,  const float* __restrict__ w_out,
    const float* __restrict__ b_out,
    const unsigned short* __restrict__ wout16, int use16,
    float* __restrict__ out, float* __restrict__ fws)
{
    cg::grid_group grid = cg::this_grid();
    const int tid   = threadIdx.x;
    const int lane  = tid & 63;
    const int wib   = tid >> 6;
    const int nwave = (gridDim.x * NT) >> 6;
    const int gw    = (blockIdx.x * NT + tid) >> 6;

    // global workspace (floats)
    float* G1  = fws;            // [2][4096] double-buffered gates1
    float* G2a = fws + 8192;     // 4096 (w_ih2 part + biases)
    float* G2b = fws + 12288;    // 4096 (w_hh2 part)
    float* PM  = fws + 16384;    // [MAXNB]
    float* PS  = PM + MAXNB;     // [MAXNB]

    // per-block replicated state (blocks compute bit-identical values)
    __shared__ float sX[XLEN];           // h1 | emb-word
    __shared__ float sC1[HID], sH2[HID], sC2[HID];
    __shared__ float sRm[NT / 64], sRs[NT / 64];
    __shared__ int   sRi[NT / 64];
    __shared__ int   sIdx;

    for (int j = tid; j < HID; j += NT) { sC1[j] = 0.f; sC2[j] = 0.f; }
    if (tid == 0) sIdx = 0;   // BOS

    //============ E1: encode gates1 = b1s + vid @ w_ih1^T  (h=0) -> G1 slot 1
    for (int r = gw; r < 4 * HID; r += nwave) {
        float v = row_dot(w_ih1 + (size_t)r * DVID, vid, DVID, lane);
        if (lane == 0) G1[4096 + r] = v + b_ih1[r] + b_hh1[r];
    }
    grid.sync();

    //============ E2: h1_e/c1_e; gates2_e (h2_old=0); gates1(0) -> G1 slot 0
    lstm_update1(G1 + 4096, sC1, sX, tid);
    for (int j = tid; j < DWORD; j += NT) sX[HID + j] = 0.f;   // pad word
    __syncthreads();
    for (int task = gw; task < 8192; task += nwave) {
        if (task < 4096) {
            int r = task;
            float v = row_dot(w_ih2 + (size_t)r * XLEN, sX, XLEN, lane);
            if (lane == 0) G2a[r] = v + b_ih2[r] + b_hh2[r];
        } else {
            int r = task - 4096;
            float v = row_dot(w_hh1 + (size_t)r * HID, sX, HID, lane);
            if (lane == 0) { G1[r] = v + b_ih1[r] + b_hh1[r]; G2b[r] = 0.f; }
        }
    }
    grid.sync();

    //============ E3: h2_e/c2_e (c=0)
    lstm_update2(G2a, G2b, sC2, sH2, tid);
    grid.sync();

    //============ decode loop: 2 grid syncs per step
    for (int t = 0; t < NSTEP; ++t) {
        //---- Phase B: finalize softmax(t-1); h1/c1 update; gates2(t); gates1(t+1)
        if (t > 0) {
            float off = block_soft_off(PM, PS, gridDim.x, tid, lane, wib, sRm, sRs);
            float* orow = out + (size_t)(t - 1) * NVOCAB;
            for (int i = blockIdx.x * NT + tid; i < NVOCAB; i += gridDim.x * NT)
                orow[i] -= off;
        }
        lstm_update1(G1 + (size_t)(t & 1) * 4096, sC1, sX, tid);
        {
            int idx = sIdx;
            const float* erow = emb + (size_t)idx * DWORD;
            for (int j = tid; j < DWORD; j += NT) sX[HID + j] = erow[j];
        }
        __syncthreads();
        for (int task = gw; task < 8192; task += nwave) {
            if (task < 4096) {
                int r = task;
                float v = row_dot(w_ih2 + (size_t)r * XLEN, sX, XLEN, lane);
                if (lane == 0) G2a[r] = v + b_ih2[r] + b_hh2[r];
            } else {
                int r = task - 4096;
                float v = row_dot(w_hh2 + (size_t)r * HID, sH2, HID, lane);
                if (lane == 0) G2b[r] = v;
                if (t < NSTEP - 1) {
                    float v1 = row_dot(w_hh1 + (size_t)r * HID, sX, HID, lane);
                    if (lane == 0) G1[(size_t)((t + 1) & 1) * 4096 + r] = v1 + b_ih1[r] + b_hh1[r];
                }
            }
        }
        grid.sync();

        //---- Phase C: h2/c2 update; argmax(h2) (block-local); logits + partials
        lstm_update2(G2a, G2b, sC2, sH2, tid);
        __syncthreads();
        {
            float bm = NEG_BIG; int bi = 0;
            for (int j = tid; j < HID; j += NT) {
                float v = sH2[j];
                if (v > bm) { bm = v; bi = j; }
            }
#pragma unroll
            for (int o = 32; o; o >>= 1) {
                float vm = __shfl_xor(bm, o, 64); int vi = __shfl_xor(bi, o, 64);
                if (vm > bm || (vm == bm && vi < bi)) { bm = vm; bi = vi; }
            }
            if (lane == 0) { sRm[wib] = bm; sRi[wib] = bi; }
            __syncthreads();
            if (tid == 0) {
                float m0 = sRm[0]; int i0 = sRi[0];
                for (int w = 1; w < NT / 64; ++w)
                    if (sRm[w] > m0 || (sRm[w] == m0 && sRi[w] < i0)) { m0 = sRm[w]; i0 = sRi[w]; }
                sIdx = i0;
            }
            __syncthreads();
        }
        {
            float* orow = out + (size_t)t * NVOCAB;
            float m = NEG_BIG, s = 0.f;
            if (use16) {
                for (int r = gw; r < NVOCAB; r += nwave) {
                    float v = row_dot_bf16(wout16 + (size_t)r * HID, sH2, lane) + b_out[r];
                    if (lane == 0) orow[r] = v;
                    if (v > m) { s = s * __expf(m - v) + 1.f; m = v; } else s += __expf(v - m);
                }
            } else {
                for (int r = gw; r < NVOCAB; r += nwave) {
                    float v = row_dot(w_out + (size_t)r * HID, sH2, HID, lane) + b_out[r];
                    if (lane == 0) orow[r] = v;
                    if (v > m) { s = s * __expf(m - v) + 1.f; m = v; } else s += __expf(v - m);
                }
            }
            if (lane == 0) { sRm[wib] = m; sRs[wib] = s; }
            __syncthreads();
            if (tid == 0) {
                float M = sRm[0], S = sRs[0];
                for (int w = 1; w < NT / 64; ++w) smax_comb(M, S, sRm[w], sRs[w]);
                PM[blockIdx.x] = M; PS[blockIdx.x] = S;
            }
        }
        grid.sync();
    }

    //============ finalize softmax for last step
    {
        float off = block_soft_off(PM, PS, gridDim.x, tid, lane, wib, sRm, sRs);
        float* orow = out + (size_t)(NSTEP - 1) * NVOCAB;
        for (int i = blockIdx.x * NT + tid; i < NVOCAB; i += gridDim.x * NT)
            orow[i] -= off;
    }
}

extern "C" void kernel_launch(void* const* d_in, const int* in_sizes, int n_in,
                              void* d_out, int out_size, void* d_ws, size_t ws_size,
                              hipStream_t stream) {
    const float* vid   = (const float*)d_in[0];
    const float* w_ih1 = (const float*)d_in[1];
    const float* w_hh1 = (const float*)d_in[2];
    const float* b_ih1 = (const float*)d_in[3];
    const float* b_hh1 = (const float*)d_in[4];
    const float* w_ih2 = (const float*)d_in[5];
    const float* w_hh2 = (const float*)d_in[6];
    const float* b_ih2 = (const float*)d_in[7];
    const float* b_hh2 = (const float*)d_in[8];
    const float* emb   = (const float*)d_in[9];
    const float* w_out = (const float*)d_in[10];
    const float* b_out = (const float*)d_in[11];
    float* out = (float*)d_out;

    const size_t WOUT_BYTES = (size_t)NVOCAB * HID * 2;            // 65.536 MB
    const size_t FWS_BYTES  = (size_t)(16384 + 2 * MAXNB) * 4;     // gates + partials
    int use16 = (ws_size >= WOUT_BYTES + FWS_BYTES) ? 1 : 0;
    unsigned short* wout16 = (unsigned short*)d_ws;
    float* fws = use16 ? (float*)((char*)d_ws + WOUT_BYTES) : (float*)d_ws;

    if (use16) {
        int n = NVOCAB * HID;                       // 32,768,000
        cvt_kernel<<<dim3(n / 1024), dim3(256), 0, stream>>>(w_out, wout16, n);
    }

    int occ = 0;
    if (hipOccupancyMaxActiveBlocksPerMultiprocessor(&occ, seq2seq_kernel, NT, 0) != hipSuccess || occ < 1)
        occ = 2;
    int nb = occ * 256;
    if (nb > MAXNB) nb = MAXNB;

    void* args[] = { &vid, &w_ih1, &w_hh1, &b_ih1, &b_hh1,
                     &w_ih2, &w_hh2, &b_ih2, &b_hh2,
                     &emb, &w_out, &b_out, &wout16, &use16, &out, &fws };
    hipLaunchCooperativeKernel((const void*)seq2seq_kernel,
                               dim3(nb), dim3(NT), args, 0, stream);
}

// Round 3
// 5180.719 us; speedup vs baseline: 1.9638x; 1.9638x over previous
//
#include <hip/hip_runtime.h>

#define HID    1024
#define DVID   4096
#define DWORD  512
#define XLEN   (HID + DWORD)
#define NVOCAB 32000
#define NSTEP  39          // MAX_LEN - 1
#define NT     256
#define NWPB   (NT / 64)
#define NEG_BIG (-3.402823466e38f)

// ---- workspace layout (bytes) ----
// ctrl[0]=rec barrier ctr, ctrl[1]=h2 step flag, ctrl[2]=logits barrier ctr
#define CTRL_BYTES 256
#define G1_OFF   256                         // [2][4096] f
#define G2A_OFF  (G1_OFF  + 32768)           // [2][4096] f
#define G2B_OFF  (G2A_OFF + 32768)           // [2][4096] f
#define H2B_OFF  (G2B_OFF + 32768)           // [39][1024] f
#define PM_OFF   (H2B_OFF + 159744)          // [39][512] f
#define PS_OFF   (PM_OFF  + 79872)           // [39][512] f
#define W16_OFF  (PS_OFF  + 79872)           // bf16 w_out
#define W16_BYTES ((size_t)NVOCAB * HID * 2)
#define WS_NEED   ((size_t)W16_OFF + W16_BYTES)

__device__ __forceinline__ float fast_sigmoid(float x) { return 1.f / (1.f + __expf(-x)); }
__device__ __forceinline__ float fast_tanh(float x)    { return 1.f - 2.f / (__expf(2.f * x) + 1.f); }

__device__ __forceinline__ float wave_reduce(float v) {
#pragma unroll
    for (int o = 32; o; o >>= 1) v += __shfl_xor(v, o, 64);
    return v;
}

__device__ __forceinline__ void smax_comb(float& M, float& S, float m2, float s2) {
    float nm = fmaxf(M, m2);
    S = S * __expf(M - nm) + s2 * __expf(m2 - nm);
    M = nm;
}

__device__ __forceinline__ void online_upd(float& m, float& s, float v) {
    if (v > m) { s = s * __expf(m - v) + 1.f; m = v; } else s += __expf(v - m);
}

// one wave: dot(w[0:len), x[0:len)); len multiple of 256
__device__ __forceinline__ float row_dot(const float* __restrict__ w, const float* x, int len, int lane) {
    float a = 0.f;
    for (int q = lane * 4; q < len; q += 256) {
        float4 wv = *(const float4*)(w + q);
        float4 xv = *(const float4*)(x + q);
        a = fmaf(wv.x, xv.x, a); a = fmaf(wv.y, xv.y, a);
        a = fmaf(wv.z, xv.z, a); a = fmaf(wv.w, xv.w, a);
    }
    return wave_reduce(a);
}

// two independent 1024-dots, loads interleaved for MLP
__device__ __forceinline__ void row_dot2(const float* __restrict__ wa, const float* xa,
                                         const float* __restrict__ wb, const float* xb,
                                         int lane, float& ra, float& rb) {
    float a = 0.f, b = 0.f;
#pragma unroll
    for (int q = lane * 4; q < HID; q += 256) {
        float4 w1 = *(const float4*)(wa + q);
        float4 w2 = *(const float4*)(wb + q);
        float4 x1 = *(const float4*)(xa + q);
        float4 x2 = *(const float4*)(xb + q);
        a = fmaf(w1.x, x1.x, a); a = fmaf(w1.y, x1.y, a);
        a = fmaf(w1.z, x1.z, a); a = fmaf(w1.w, x1.w, a);
        b = fmaf(w2.x, x2.x, b); b = fmaf(w2.y, x2.y, b);
        b = fmaf(w2.z, x2.z, b); b = fmaf(w2.w, x2.w, b);
    }
    ra = wave_reduce(a); rb = wave_reduce(b);
}

__device__ __forceinline__ float bflo(unsigned u) { return __uint_as_float(u << 16); }
__device__ __forceinline__ float bfhi(unsigned u) { return __uint_as_float(u & 0xffff0000u); }

// 4 consecutive bf16 rows (stride HID) against fp32 x; 8 global loads in flight
__device__ __forceinline__ void dot4_bf16(const unsigned short* __restrict__ w, const float* x,
                                          int lane, float& r0, float& r1, float& r2, float& r3) {
    float a0 = 0.f, a1 = 0.f, a2 = 0.f, a3 = 0.f;
#pragma unroll
    for (int q = lane * 8; q < HID; q += 512) {
        uint4 u0 = *(const uint4*)(w + q);
        uint4 u1 = *(const uint4*)(w + HID + q);
        uint4 u2 = *(const uint4*)(w + 2 * HID + q);
        uint4 u3 = *(const uint4*)(w + 3 * HID + q);
        float4 x0 = *(const float4*)(x + q);
        float4 x1 = *(const float4*)(x + q + 4);
        a0 = fmaf(bflo(u0.x), x0.x, a0); a0 = fmaf(bfhi(u0.x), x0.y, a0);
        a0 = fmaf(bflo(u0.y), x0.z, a0); a0 = fmaf(bfhi(u0.y), x0.w, a0);
        a0 = fmaf(bflo(u0.z), x1.x, a0); a0 = fmaf(bfhi(u0.z), x1.y, a0);
        a0 = fmaf(bflo(u0.w), x1.z, a0); a0 = fmaf(bfhi(u0.w), x1.w, a0);
        a1 = fmaf(bflo(u1.x), x0.x, a1); a1 = fmaf(bfhi(u1.x), x0.y, a1);
        a1 = fmaf(bflo(u1.y), x0.z, a1); a1 = fmaf(bfhi(u1.y), x0.w, a1);
        a1 = fmaf(bflo(u1.z), x1.x, a1); a1 = fmaf(bfhi(u1.z), x1.y, a1);
        a1 = fmaf(bflo(u1.w), x1.z, a1); a1 = fmaf(bfhi(u1.w), x1.w, a1);
        a2 = fmaf(bflo(u2.x), x0.x, a2); a2 = fmaf(bfhi(u2.x), x0.y, a2);
        a2 = fmaf(bflo(u2.y), x0.z, a2); a2 = fmaf(bfhi(u2.y), x0.w, a2);
        a2 = fmaf(bflo(u2.z), x1.x, a2); a2 = fmaf(bfhi(u2.z), x1.y, a2);
        a2 = fmaf(bflo(u2.w), x1.z, a2); a2 = fmaf(bfhi(u2.w), x1.w, a2);
        a3 = fmaf(bflo(u3.x), x0.x, a3); a3 = fmaf(bfhi(u3.x), x0.y, a3);
        a3 = fmaf(bflo(u3.y), x0.z, a3); a3 = fmaf(bfhi(u3.y), x0.w, a3);
        a3 = fmaf(bflo(u3.z), x1.x, a3); a3 = fmaf(bfhi(u3.z), x1.y, a3);
        a3 = fmaf(bflo(u3.w), x1.z, a3); a3 = fmaf(bfhi(u3.w), x1.w, a3);
    }
    r0 = wave_reduce(a0); r1 = wave_reduce(a1);
    r2 = wave_reduce(a2); r3 = wave_reduce(a3);
}

__device__ __forceinline__ float dot1_bf16(const unsigned short* __restrict__ w, const float* x, int lane) {
    float a = 0.f;
#pragma unroll
    for (int q = lane * 8; q < HID; q += 512) {
        uint4  u  = *(const uint4*)(w + q);
        float4 x0 = *(const float4*)(x + q);
        float4 x1 = *(const float4*)(x + q + 4);
        a = fmaf(bflo(u.x), x0.x, a); a = fmaf(bfhi(u.x), x0.y, a);
        a = fmaf(bflo(u.y), x0.z, a); a = fmaf(bfhi(u.y), x0.w, a);
        a = fmaf(bflo(u.z), x1.x, a); a = fmaf(bfhi(u.z), x1.y, a);
        a = fmaf(bflo(u.w), x1.z, a); a = fmaf(bfhi(u.w), x1.w, a);
    }
    return wave_reduce(a);
}

__device__ __forceinline__ void lstm_update1(const float* __restrict__ G, float* c, float* h, int tid) {
    for (int j = tid; j < HID; j += NT) {
        float gi = G[j], gf = G[j + HID], gg = G[j + 2 * HID], go = G[j + 3 * HID];
        float cn = fast_sigmoid(gf) * c[j] + fast_sigmoid(gi) * fast_tanh(gg);
        c[j] = cn;
        h[j] = fast_sigmoid(go) * fast_tanh(cn);
    }
}

__device__ __forceinline__ void lstm_update2(const float* __restrict__ Ga, const float* __restrict__ Gb,
                                             float* c, float* h, int tid) {
    for (int j = tid; j < HID; j += NT) {
        float gi = Ga[j] + Gb[j];
        float gf = Ga[j + HID] + Gb[j + HID];
        float gg = Ga[j + 2 * HID] + Gb[j + 2 * HID];
        float go = Ga[j + 3 * HID] + Gb[j + 3 * HID];
        float cn = fast_sigmoid(gf) * c[j] + fast_sigmoid(gi) * fast_tanh(gg);
        c[j] = cn;
        h[j] = fast_sigmoid(go) * fast_tanh(cn);
    }
}

// monotonic group barrier: nblk arrivals per generation, spin by tid0 only
__device__ __forceinline__ void group_barrier(unsigned* ctr, unsigned target, int tid) {
    __syncthreads();
    if (tid == 0) {
        __threadfence();
        __hip_atomic_fetch_add(ctr, 1u, __ATOMIC_RELEASE, __HIP_MEMORY_SCOPE_AGENT);
        while (__hip_atomic_load(ctr, __ATOMIC_ACQUIRE, __HIP_MEMORY_SCOPE_AGENT) < target)
            __builtin_amdgcn_s_sleep(2);
        __threadfence();
    }
    __syncthreads();
}

__device__ __forceinline__ unsigned short f2bf(float f) {
    unsigned u = __float_as_uint(f);
    u += 0x7fffu + ((u >> 16) & 1u);
    return (unsigned short)(u >> 16);
}

__global__ void cvt_kernel(const float* __restrict__ w, unsigned short* __restrict__ o, int n) {
    int i = (blockIdx.x * 256 + threadIdx.x) * 4;
    if (i >= n) return;
    float4 v = *(const float4*)(w + i);
    ushort4 r;
    r.x = f2bf(v.x); r.y = f2bf(v.y); r.z = f2bf(v.z); r.w = f2bf(v.w);
    *(ushort4*)(o + i) = r;
}

__global__ __launch_bounds__(NT, 4) void seq2seq_kernel(
    const float* __restrict__ vid,
    const float* __restrict__ w_ih1, const float* __restrict__ w_hh1,
    const float* __restrict__ b_ih1, const float* __restrict__ b_hh1,
    const float* __restrict__ w_ih2, const float* __restrict__ w_hh2,
    const float* __restrict__ b_ih2, const float* __restrict__ b_hh2,
    const float* __restrict__ emb,  const float* __restrict__ w_out,
    const float* __restrict__ b_out,
    int use16, int nr, int nl,
    float* __restrict__ out, char* wsb)
{
    const int tid  = threadIdx.x;
    const int lane = tid & 63;
    const int wib  = tid >> 6;

    unsigned* rbar   = (unsigned*)wsb + 0;
    unsigned* h2step = (unsigned*)wsb + 1;
    unsigned* lbar   = (unsigned*)wsb + 2;
    float* G1g = (float*)(wsb + G1_OFF);
    float* G2a = (float*)(wsb + G2A_OFF);
    float* G2b = (float*)(wsb + G2B_OFF);
    float* h2b = (float*)(wsb + H2B_OFF);
    float* PM  = (float*)(wsb + PM_OFF);
    float* PS  = (float*)(wsb + PS_OFF);
    const unsigned short* w16 = (const unsigned short*)(wsb + W16_OFF);

    __shared__ float sX[XLEN];          // h1 | emb  (logits group: h2 staging)
    __shared__ float sC1[HID], sC2[HID], sH2[HID];
    __shared__ float sRm[NWPB], sRs[NWPB];
    __shared__ int   sRi[NWPB];
    __shared__ int   sIdx;

    const bool is_rec = (blockIdx.x & 1) == 0;

    if (is_rec) {
        //==================== RECURRENCE GROUP ====================
        const int rb  = blockIdx.x >> 1;            // 0..nr-1
        const int nwr = nr * NWPB;
        const int gw  = rb * NWPB + wib;
        unsigned bk = 0;

        for (int j = tid; j < HID; j += NT) { sC1[j] = 0.f; sC2[j] = 0.f; }
        if (tid == 0) sIdx = 0;
        __syncthreads();

        // E1: G1_e = b1s + vid @ w_ih1^T  -> G1 slot 1
        {
            int chunk = (4096 + nwr - 1) / nwr;
            int b0 = gw * chunk, e0 = b0 + chunk; if (e0 > 4096) e0 = 4096;
            for (int r = b0; r < e0; ++r) {
                float v = row_dot(w_ih1 + (size_t)r * DVID, vid, DVID, lane);
                if (lane == 0) G1g[4096 + r] = v + b_ih1[r] + b_hh1[r];
            }
        }
        group_barrier(rbar, nr * (++bk), tid);

        // E2: h1_e local; G2a_e (slot1) + G1(0) (slot0); G2b_e = 0
        lstm_update1(G1g + 4096, sC1, sX, tid);
        for (int j = tid; j < DWORD; j += NT) sX[HID + j] = 0.f;
        __syncthreads();
        {
            int chunk = (8192 + nwr - 1) / nwr;
            int b0 = gw * chunk, e0 = b0 + chunk; if (e0 > 8192) e0 = 8192;
            for (int task = b0; task < e0; ++task) {
                if (task < 4096) {
                    int r = task;
                    float v = row_dot(w_ih2 + (size_t)r * XLEN, sX, XLEN, lane);
                    if (lane == 0) G2a[4096 + r] = v + b_ih2[r] + b_hh2[r];
                } else {
                    int r = task - 4096;
                    float v = row_dot(w_hh1 + (size_t)r * HID, sX, HID, lane);
                    if (lane == 0) { G1g[r] = v + b_ih1[r] + b_hh1[r]; G2b[4096 + r] = 0.f; }
                }
            }
        }
        group_barrier(rbar, nr * (++bk), tid);

        // E3: h2_e local (c2=0)
        lstm_update2(G2a + 4096, G2b + 4096, sC2, sH2, tid);
        __syncthreads();

        for (int t = 0; t < NSTEP; ++t) {
            const int cb = (t & 1) * 4096, nb2 = ((t + 1) & 1) * 4096;
            // local: h1(t) from G1[t&1]; x = [h1, emb[idx]]
            lstm_update1(G1g + cb, sC1, sX, tid);
            {
                const float* erow = emb + (size_t)sIdx * DWORD;
                for (int j = tid; j < DWORD; j += NT) sX[HID + j] = erow[j];
            }
            __syncthreads();
            // matvecs: G2a/G2b[t&1], G1[(t+1)&1]
            {
                int chunk = (8192 + nwr - 1) / nwr;
                int b0 = gw * chunk, e0 = b0 + chunk; if (e0 > 8192) e0 = 8192;
                for (int task = b0; task < e0; ++task) {
                    if (task < 4096) {
                        int r = task;
                        float v = row_dot(w_ih2 + (size_t)r * XLEN, sX, XLEN, lane);
                        if (lane == 0) G2a[cb + r] = v + b_ih2[r] + b_hh2[r];
                    } else {
                        int r = task - 4096;
                        float va, vb;
                        row_dot2(w_hh2 + (size_t)r * HID, sH2,
                                 w_hh1 + (size_t)r * HID, sX, lane, va, vb);
                        if (lane == 0) {
                            G2b[cb + r] = va;
                            if (t < NSTEP - 1) G1g[nb2 + r] = vb + b_ih1[r] + b_hh1[r];
                        }
                    }
                }
            }
            group_barrier(rbar, nr * (++bk), tid);

            // local: h2(t)/c2(t); publish h2 (block 0); argmax -> sIdx
            lstm_update2(G2a + cb, G2b + cb, sC2, sH2, tid);
            __syncthreads();
            if (blockIdx.x == 0)
                for (int i = tid * 4; i < HID; i += NT * 4)
                    *(float4*)(h2b + (size_t)t * HID + i) = *(const float4*)(sH2 + i);
            {
                float bm = NEG_BIG; int bi = 0;
                for (int j = tid; j < HID; j += NT) {
                    float v = sH2[j];
                    if (v > bm) { bm = v; bi = j; }
                }
#pragma unroll
                for (int o = 32; o; o >>= 1) {
                    float vm = __shfl_xor(bm, o, 64); int vi = __shfl_xor(bi, o, 64);
                    if (vm > bm || (vm == bm && vi < bi)) { bm = vm; bi = vi; }
                }
                if (lane == 0) { sRm[wib] = bm; sRi[wib] = bi; }
                __syncthreads();
                if (tid == 0) {
                    float m0 = sRm[0]; int i0 = sRi[0];
                    for (int w = 1; w < NWPB; ++w)
                        if (sRm[w] > m0 || (sRm[w] == m0 && sRi[w] < i0)) { m0 = sRm[w]; i0 = sRi[w]; }
                    sIdx = i0;
                }
            }
            __syncthreads();
            if (blockIdx.x == 0 && tid == 0) {
                __threadfence();
                __hip_atomic_store(h2step, (unsigned)(t + 1), __ATOMIC_RELEASE, __HIP_MEMORY_SCOPE_AGENT);
            }
        }
    } else {
        //==================== LOGITS GROUP ====================
        const int lb  = blockIdx.x >> 1;            // 0..nl-1
        const int nwl = nl * NWPB;
        const int gw  = lb * NWPB + wib;
        const int chunk = (NVOCAB + nwl - 1) / nwl;
        const int begin = gw * chunk;
        const int end   = (begin + chunk < NVOCAB) ? begin + chunk : NVOCAB;

        for (int t = 0; t < NSTEP; ++t) {
            if (tid == 0) {
                while (__hip_atomic_load(h2step, __ATOMIC_ACQUIRE, __HIP_MEMORY_SCOPE_AGENT) < (unsigned)(t + 1))
                    __builtin_amdgcn_s_sleep(2);
                __threadfence();
            }
            __syncthreads();
            for (int i = tid * 4; i < HID; i += NT * 4)
                *(float4*)(sX + i) = *(const float4*)(h2b + (size_t)t * HID + i);
            __syncthreads();

            float* orow = out + (size_t)t * NVOCAB;
            float m = NEG_BIG, s = 0.f;
            if (use16) {
                int r = begin;
                for (; r + 4 <= end; r += 4) {
                    float v0, v1, v2, v3;
                    dot4_bf16(w16 + (size_t)r * HID, sX, lane, v0, v1, v2, v3);
                    v0 += b_out[r]; v1 += b_out[r + 1]; v2 += b_out[r + 2]; v3 += b_out[r + 3];
                    if (lane == 0) { orow[r] = v0; orow[r + 1] = v1; orow[r + 2] = v2; orow[r + 3] = v3; }
                    online_upd(m, s, v0); online_upd(m, s, v1);
                    online_upd(m, s, v2); online_upd(m, s, v3);
                }
                for (; r < end; ++r) {
                    float v = dot1_bf16(w16 + (size_t)r * HID, sX, lane) + b_out[r];
                    if (lane == 0) orow[r] = v;
                    online_upd(m, s, v);
                }
            } else {
                int r = begin;
                for (; r + 2 <= end; r += 2) {
                    float v0, v1;
                    row_dot2(w_out + (size_t)r * HID, sX, w_out + (size_t)(r + 1) * HID, sX, lane, v0, v1);
                    v0 += b_out[r]; v1 += b_out[r + 1];
                    if (lane == 0) { orow[r] = v0; orow[r + 1] = v1; }
                    online_upd(m, s, v0); online_upd(m, s, v1);
                }
                for (; r < end; ++r) {
                    float v = row_dot(w_out + (size_t)r * HID, sX, HID, lane) + b_out[r];
                    if (lane == 0) orow[r] = v;
                    online_upd(m, s, v);
                }
            }
            // block partials -> PM/PS[t][lb], arrive at logits barrier
            if (lane == 0) { sRm[wib] = m; sRs[wib] = s; }
            __syncthreads();
            if (tid == 0) {
                float M = sRm[0], S = sRs[0];
                for (int w = 1; w < NWPB; ++w) smax_comb(M, S, sRm[w], sRs[w]);
                PM[t * 512 + lb] = M; PS[t * 512 + lb] = S;
                __threadfence();
                __hip_atomic_fetch_add(lbar, 1u, __ATOMIC_RELEASE, __HIP_MEMORY_SCOPE_AGENT);
                while (__hip_atomic_load(lbar, __ATOMIC_ACQUIRE, __HIP_MEMORY_SCOPE_AGENT) < (unsigned)(nl * (t + 1)))
                    __builtin_amdgcn_s_sleep(2);
                __threadfence();
            }
            __syncthreads();
            // combined offset over all nl partials
            {
                float M = NEG_BIG, S = 0.f;
                for (int i = tid; i < nl; i += NT) smax_comb(M, S, PM[t * 512 + i], PS[t * 512 + i]);
#pragma unroll
                for (int o = 32; o; o >>= 1) {
                    float m2 = __shfl_xor(M, o, 64), s2 = __shfl_xor(S, o, 64);
                    smax_comb(M, S, m2, s2);
                }
                if (lane == 0) { sRm[wib] = M; sRs[wib] = S; }
                __syncthreads();
                M = sRm[0]; S = sRs[0];
                for (int w = 1; w < NWPB; ++w) smax_comb(M, S, sRm[w], sRs[w]);
                float off = M + __logf(S);
                for (int i = begin + lane; i < end; i += 64) orow[i] -= off;
            }
            __syncthreads();
        }
    }
}

extern "C" void kernel_launch(void* const* d_in, const int* in_sizes, int n_in,
                              void* d_out, int out_size, void* d_ws, size_t ws_size,
                              hipStream_t stream) {
    const float* vid   = (const float*)d_in[0];
    const float* w_ih1 = (const float*)d_in[1];
    const float* w_hh1 = (const float*)d_in[2];
    const float* b_ih1 = (const float*)d_in[3];
    const float* b_hh1 = (const float*)d_in[4];
    const float* w_ih2 = (const float*)d_in[5];
    const float* w_hh2 = (const float*)d_in[6];
    const float* b_ih2 = (const float*)d_in[7];
    const float* b_hh2 = (const float*)d_in[8];
    const float* emb   = (const float*)d_in[9];
    const float* w_out = (const float*)d_in[10];
    const float* b_out = (const float*)d_in[11];
    float* out = (float*)d_out;
    char* wsb  = (char*)d_ws;

    int use16 = (ws_size >= WS_NEED) ? 1 : 0;

    // zero the barrier/flag control words (ws is poisoned 0xAA before each launch)
    hipMemsetAsync(d_ws, 0, CTRL_BYTES, stream);

    if (use16) {
        int n = NVOCAB * HID;
        cvt_kernel<<<dim3(n / 1024), dim3(256), 0, stream>>>(
            w_out, (unsigned short*)(wsb + W16_OFF), n);
    }

    int occ = 0;
    if (hipOccupancyMaxActiveBlocksPerMultiprocessor(&occ, seq2seq_kernel, NT, 0) != hipSuccess || occ < 1)
        occ = 1;
    int nb = occ * 256;
    if (nb > 1024) nb = 1024;
    nb &= ~1;                       // even: parity split
    int nr = nb / 2, nl = nb / 2;

    void* args[] = { &vid, &w_ih1, &w_hh1, &b_ih1, &b_hh1,
                     &w_ih2, &w_hh2, &b_ih2, &b_hh2,
                     &emb, &w_out, &b_out, &use16, &nr, &nl, &out, &wsb };
    hipLaunchCooperativeKernel((const void*)seq2seq_kernel,
                               dim3(nb), dim3(NT), args, 0, stream);
}

// Round 4
// 4136.373 us; speedup vs baseline: 2.4596x; 1.2525x over previous
//
#include <hip/hip_runtime.h>

#define HID    1024
#define DVID   4096
#define DWORD  512
#define XLEN   (HID + DWORD)
#define NVOCAB 32000
#define NSTEP  39          // MAX_LEN - 1
#define NT     256
#define NWPB   (NT / 64)
#define NEG_BIG (-3.402823466e38f)

// ---- workspace layout ----
// Control words each live on their own 128B line to kill false sharing.
#define CTRL_BYTES 65536
#define RBAR_W   0                    // rec barrier counter (word idx)
#define H2F_W    256                  // h2 flag replicas: word 256 + i*32, i<8
#define LBAR_W   1024                 // lbar[t][s]: word 1024 + t*256 + s*32
#define G1_OFF   65536                // [2][4096] f
#define G2A_OFF  (G1_OFF  + 32768)    // [2][4096] f
#define G2B_OFF  (G2A_OFF + 32768)    // [2][4096] f
#define H2B_OFF  (G2B_OFF + 32768)    // [39][1024] f
#define PM_OFF   (H2B_OFF + 159744)   // [39][1024] f
#define PS_OFF   (PM_OFF  + 159744)   // [39][1024] f
#define W16_OFF  (PS_OFF  + 159744)   // bf16 w_out (row-major)
#define W16_BYTES ((size_t)NVOCAB * HID * 2)
#define WS_NEED   ((size_t)W16_OFF + W16_BYTES)

__device__ __forceinline__ float fast_sigmoid(float x) { return 1.f / (1.f + __expf(-x)); }
__device__ __forceinline__ float fast_tanh(float x)    { return 1.f - 2.f / (__expf(2.f * x) + 1.f); }

__device__ __forceinline__ float wave_reduce(float v) {
#pragma unroll
    for (int o = 32; o; o >>= 1) v += __shfl_xor(v, o, 64);
    return v;
}
__device__ __forceinline__ int wave_reduce_i(int v) {
#pragma unroll
    for (int o = 32; o; o >>= 1) v += __shfl_xor(v, o, 64);
    return v;
}

__device__ __forceinline__ void smax_comb(float& M, float& S, float m2, float s2) {
    float nm = fmaxf(M, m2);
    S = S * __expf(M - nm) + s2 * __expf(m2 - nm);
    M = nm;
}
__device__ __forceinline__ void online_upd(float& m, float& s, float v) {
    if (v > m) { s = s * __expf(m - v) + 1.f; m = v; } else s += __expf(v - m);
}

// one wave: dot(w[0:LEN), x[0:LEN)); LEN multiple of 256; fully unrolled
template<int LEN>
__device__ __forceinline__ float row_dotT(const float* __restrict__ w, const float* x, int lane) {
    float a = 0.f;
#pragma unroll
    for (int q = lane * 4; q < LEN; q += 256) {
        float4 wv = *(const float4*)(w + q);
        float4 xv = *(const float4*)(x + q);
        a = fmaf(wv.x, xv.x, a); a = fmaf(wv.y, xv.y, a);
        a = fmaf(wv.z, xv.z, a); a = fmaf(wv.w, xv.w, a);
    }
    return wave_reduce(a);
}

// two independent 1024-dots, loads interleaved
__device__ __forceinline__ void row_dot2(const float* __restrict__ wa, const float* xa,
                                         const float* __restrict__ wb, const float* xb,
                                         int lane, float& ra, float& rb) {
    float a = 0.f, b = 0.f;
#pragma unroll
    for (int q = lane * 4; q < HID; q += 256) {
        float4 w1 = *(const float4*)(wa + q);
        float4 w2 = *(const float4*)(wb + q);
        float4 x1 = *(const float4*)(xa + q);
        float4 x2 = *(const float4*)(xb + q);
        a = fmaf(w1.x, x1.x, a); a = fmaf(w1.y, x1.y, a);
        a = fmaf(w1.z, x1.z, a); a = fmaf(w1.w, x1.w, a);
        b = fmaf(w2.x, x2.x, b); b = fmaf(w2.y, x2.y, b);
        b = fmaf(w2.z, x2.z, b); b = fmaf(w2.w, x2.w, b);
    }
    ra = wave_reduce(a); rb = wave_reduce(b);
}

__device__ __forceinline__ float bflo(unsigned u) { return __uint_as_float(u << 16); }
__device__ __forceinline__ float bfhi(unsigned u) { return __uint_as_float(u & 0xffff0000u); }

// 4 consecutive bf16 rows (stride HID) vs fp32 x
__device__ __forceinline__ void dot4_bf16(const unsigned short* __restrict__ w, const float* x,
                                          int lane, float& r0, float& r1, float& r2, float& r3) {
    float a0 = 0.f, a1 = 0.f, a2 = 0.f, a3 = 0.f;
#pragma unroll
    for (int q = lane * 8; q < HID; q += 512) {
        uint4 u0 = *(const uint4*)(w + q);
        uint4 u1 = *(const uint4*)(w + HID + q);
        uint4 u2 = *(const uint4*)(w + 2 * HID + q);
        uint4 u3 = *(const uint4*)(w + 3 * HID + q);
        float4 x0 = *(const float4*)(x + q);
        float4 x1 = *(const float4*)(x + q + 4);
        a0 = fmaf(bflo(u0.x), x0.x, a0); a0 = fmaf(bfhi(u0.x), x0.y, a0);
        a0 = fmaf(bflo(u0.y), x0.z, a0); a0 = fmaf(bfhi(u0.y), x0.w, a0);
        a0 = fmaf(bflo(u0.z), x1.x, a0); a0 = fmaf(bfhi(u0.z), x1.y, a0);
        a0 = fmaf(bflo(u0.w), x1.z, a0); a0 = fmaf(bfhi(u0.w), x1.w, a0);
        a1 = fmaf(bflo(u1.x), x0.x, a1); a1 = fmaf(bfhi(u1.x), x0.y, a1);
        a1 = fmaf(bflo(u1.y), x0.z, a1); a1 = fmaf(bfhi(u1.y), x0.w, a1);
        a1 = fmaf(bflo(u1.z), x1.x, a1); a1 = fmaf(bfhi(u1.z), x1.y, a1);
        a1 = fmaf(bflo(u1.w), x1.z, a1); a1 = fmaf(bfhi(u1.w), x1.w, a1);
        a2 = fmaf(bflo(u2.x), x0.x, a2); a2 = fmaf(bfhi(u2.x), x0.y, a2);
        a2 = fmaf(bflo(u2.y), x0.z, a2); a2 = fmaf(bfhi(u2.y), x0.w, a2);
        a2 = fmaf(bflo(u2.z), x1.x, a2); a2 = fmaf(bfhi(u2.z), x1.y, a2);
        a2 = fmaf(bflo(u2.w), x1.z, a2); a2 = fmaf(bfhi(u2.w), x1.w, a2);
        a3 = fmaf(bflo(u3.x), x0.x, a3); a3 = fmaf(bfhi(u3.x), x0.y, a3);
        a3 = fmaf(bflo(u3.y), x0.z, a3); a3 = fmaf(bfhi(u3.y), x0.w, a3);
        a3 = fmaf(bflo(u3.z), x1.x, a3); a3 = fmaf(bfhi(u3.z), x1.y, a3);
        a3 = fmaf(bflo(u3.w), x1.z, a3); a3 = fmaf(bfhi(u3.w), x1.w, a3);
    }
    r0 = wave_reduce(a0); r1 = wave_reduce(a1);
    r2 = wave_reduce(a2); r3 = wave_reduce(a3);
}

__device__ __forceinline__ float dot1_bf16(const unsigned short* __restrict__ w, const float* x, int lane) {
    float a = 0.f;
#pragma unroll
    for (int q = lane * 8; q < HID; q += 512) {
        uint4  u  = *(const uint4*)(w + q);
        float4 x0 = *(const float4*)(x + q);
        float4 x1 = *(const float4*)(x + q + 4);
        a = fmaf(bflo(u.x), x0.x, a); a = fmaf(bfhi(u.x), x0.y, a);
        a = fmaf(bflo(u.y), x0.z, a); a = fmaf(bfhi(u.y), x0.w, a);
        a = fmaf(bflo(u.z), x1.x, a); a = fmaf(bfhi(u.z), x1.y, a);
        a = fmaf(bflo(u.w), x1.z, a); a = fmaf(bfhi(u.w), x1.w, a);
    }
    return wave_reduce(a);
}

__device__ __forceinline__ void lstm_update1(const float* __restrict__ G, float* c, float* h, int tid) {
    for (int j = tid; j < HID; j += NT) {
        float gi = G[j], gf = G[j + HID], gg = G[j + 2 * HID], go = G[j + 3 * HID];
        float cn = fast_sigmoid(gf) * c[j] + fast_sigmoid(gi) * fast_tanh(gg);
        c[j] = cn;
        h[j] = fast_sigmoid(go) * fast_tanh(cn);
    }
}
__device__ __forceinline__ void lstm_update2(const float* __restrict__ Ga, const float* __restrict__ Gb,
                                             float* c, float* h, int tid) {
    for (int j = tid; j < HID; j += NT) {
        float gi = Ga[j] + Gb[j];
        float gf = Ga[j + HID] + Gb[j + HID];
        float gg = Ga[j + 2 * HID] + Gb[j + 2 * HID];
        float go = Ga[j + 3 * HID] + Gb[j + 3 * HID];
        float cn = fast_sigmoid(gf) * c[j] + fast_sigmoid(gi) * fast_tanh(gg);
        c[j] = cn;
        h[j] = fast_sigmoid(go) * fast_tanh(cn);
    }
}

// single-counter monotonic barrier, own cache line; tid0 spins with long sleep
__device__ __forceinline__ void rec_barrier(unsigned* ctr, unsigned target, int tid) {
    __syncthreads();
    if (tid == 0) {
        __threadfence();
        __hip_atomic_fetch_add(ctr, 1u, __ATOMIC_RELEASE, __HIP_MEMORY_SCOPE_AGENT);
        while (__hip_atomic_load(ctr, __ATOMIC_ACQUIRE, __HIP_MEMORY_SCOPE_AGENT) < target)
            __builtin_amdgcn_s_sleep(8);
        __threadfence();
    }
    __syncthreads();
}

__device__ __forceinline__ unsigned short f2bf(float f) {
    unsigned u = __float_as_uint(f);
    u += 0x7fffu + ((u >> 16) & 1u);
    return (unsigned short)(u >> 16);
}

__global__ void cvt_kernel(const float* __restrict__ w, unsigned short* __restrict__ o, int n) {
    int i = (blockIdx.x * 256 + threadIdx.x) * 4;
    if (i >= n) return;
    float4 v = *(const float4*)(w + i);
    ushort4 r;
    r.x = f2bf(v.x); r.y = f2bf(v.y); r.z = f2bf(v.z); r.w = f2bf(v.w);
    *(ushort4*)(o + i) = r;
}

__global__ __launch_bounds__(NT, 4) void seq2seq_kernel(
    const float* __restrict__ vid,
    const float* __restrict__ w_ih1, const float* __restrict__ w_hh1,
    const float* __restrict__ b_ih1, const float* __restrict__ b_hh1,
    const float* __restrict__ w_ih2, const float* __restrict__ w_hh2,
    const float* __restrict__ b_ih2, const float* __restrict__ b_hh2,
    const float* __restrict__ emb,  const float* __restrict__ w_out,
    const float* __restrict__ b_out,
    int use16, int nr, int nl,
    float* __restrict__ out, char* wsb)
{
    const int tid  = threadIdx.x;
    const int lane = tid & 63;
    const int wib  = tid >> 6;

    unsigned* ctrl = (unsigned*)wsb;
    unsigned* rbar = ctrl + RBAR_W;
    unsigned* h2f  = ctrl + H2F_W;          // 8 replicas, stride 32 words
    float* G1g = (float*)(wsb + G1_OFF);
    float* G2a = (float*)(wsb + G2A_OFF);
    float* G2b = (float*)(wsb + G2B_OFF);
    float* h2b = (float*)(wsb + H2B_OFF);
    float* PM  = (float*)(wsb + PM_OFF);
    float* PS  = (float*)(wsb + PS_OFF);
    const unsigned short* w16 = (const unsigned short*)(wsb + W16_OFF);

    __shared__ float sX[XLEN];
    __shared__ float sC1[HID], sC2[HID], sH2[HID];
    __shared__ float sRm[NWPB], sRs[NWPB];
    __shared__ int   sRi[NWPB];
    __shared__ int   sIdx;

    const bool is_rec = (blockIdx.x & 3) == 0;   // 1 rec : 3 logits

    if (is_rec) {
        //==================== RECURRENCE GROUP (nr blocks) ====================
        const int rb  = blockIdx.x >> 2;
        const int nwr = nr * NWPB;
        const int gw  = rb * NWPB + wib;
        unsigned bk = 0;

        for (int j = tid; j < HID; j += NT) { sC1[j] = 0.f; sC2[j] = 0.f; }
        if (tid == 0) sIdx = 0;
        __syncthreads();

        // E1: G1_e -> slot 1
        {
            int chunk = (4096 + nwr - 1) / nwr;
            int b0 = gw * chunk, e0 = b0 + chunk; if (e0 > 4096) e0 = 4096;
            for (int r = b0; r < e0; ++r) {
                float v = row_dotT<DVID>(w_ih1 + (size_t)r * DVID, vid, lane);
                if (lane == 0) G1g[4096 + r] = v + b_ih1[r] + b_hh1[r];
            }
        }
        rec_barrier(rbar, nr * (++bk), tid);

        // E2: h1_e; G2a_e (slot1), G2b_e=0; G1(0) -> slot 0
        lstm_update1(G1g + 4096, sC1, sX, tid);
        for (int j = tid; j < DWORD; j += NT) sX[HID + j] = 0.f;
        __syncthreads();
        {
            int chunk = (8192 + nwr - 1) / nwr;
            int b0 = gw * chunk, e0 = b0 + chunk; if (e0 > 8192) e0 = 8192;
            for (int task = b0; task < e0; ++task) {
                if (task < 4096) {
                    int r = task;
                    float v = row_dotT<XLEN>(w_ih2 + (size_t)r * XLEN, sX, lane);
                    if (lane == 0) G2a[4096 + r] = v + b_ih2[r] + b_hh2[r];
                } else {
                    int r = task - 4096;
                    float v = row_dotT<HID>(w_hh1 + (size_t)r * HID, sX, lane);
                    if (lane == 0) { G1g[r] = v + b_ih1[r] + b_hh1[r]; G2b[4096 + r] = 0.f; }
                }
            }
        }
        rec_barrier(rbar, nr * (++bk), tid);

        // E3: h2_e (c2=0)
        lstm_update2(G2a + 4096, G2b + 4096, sC2, sH2, tid);
        __syncthreads();

        for (int t = 0; t < NSTEP; ++t) {
            const int cb = (t & 1) * 4096, nb2 = ((t + 1) & 1) * 4096;
            lstm_update1(G1g + cb, sC1, sX, tid);
            {
                const float* erow = emb + (size_t)sIdx * DWORD;
                for (int j = tid; j < DWORD; j += NT) sX[HID + j] = erow[j];
            }
            __syncthreads();
            {
                int chunk = (8192 + nwr - 1) / nwr;
                int b0 = gw * chunk, e0 = b0 + chunk; if (e0 > 8192) e0 = 8192;
                for (int task = b0; task < e0; ++task) {
                    if (task < 4096) {
                        int r = task;
                        float v = row_dotT<XLEN>(w_ih2 + (size_t)r * XLEN, sX, lane);
                        if (lane == 0) G2a[cb + r] = v + b_ih2[r] + b_hh2[r];
                    } else {
                        int r = task - 4096;
                        float va, vb;
                        row_dot2(w_hh2 + (size_t)r * HID, sH2,
                                 w_hh1 + (size_t)r * HID, sX, lane, va, vb);
                        if (lane == 0) {
                            G2b[cb + r] = va;
                            if (t < NSTEP - 1) G1g[nb2 + r] = vb + b_ih1[r] + b_hh1[r];
                        }
                    }
                }
            }
            rec_barrier(rbar, nr * (++bk), tid);

            lstm_update2(G2a + cb, G2b + cb, sC2, sH2, tid);
            __syncthreads();
            if (blockIdx.x == 0)
                for (int i = tid * 4; i < HID; i += NT * 4)
                    *(float4*)(h2b + (size_t)t * HID + i) = *(const float4*)(sH2 + i);
            {
                float bm = NEG_BIG; int bi = 0;
                for (int j = tid; j < HID; j += NT) {
                    float v = sH2[j];
                    if (v > bm) { bm = v; bi = j; }
                }
#pragma unroll
                for (int o = 32; o; o >>= 1) {
                    float vm = __shfl_xor(bm, o, 64); int vi = __shfl_xor(bi, o, 64);
                    if (vm > bm || (vm == bm && vi < bi)) { bm = vm; bi = vi; }
                }
                if (lane == 0) { sRm[wib] = bm; sRi[wib] = bi; }
                __syncthreads();
                if (tid == 0) {
                    float m0 = sRm[0]; int i0 = sRi[0];
                    for (int w = 1; w < NWPB; ++w)
                        if (sRm[w] > m0 || (sRm[w] == m0 && sRi[w] < i0)) { m0 = sRm[w]; i0 = sRi[w]; }
                    sIdx = i0;
                }
            }
            __syncthreads();
            if (blockIdx.x == 0 && tid == 0) {
                __threadfence();
#pragma unroll
                for (int i = 0; i < 8; ++i)
                    __hip_atomic_store(h2f + i * 32, (unsigned)(t + 1),
                                       __ATOMIC_RELEASE, __HIP_MEMORY_SCOPE_AGENT);
            }
        }
    } else {
        //==================== LOGITS GROUP (nl blocks) ====================
        const int lb  = blockIdx.x - (blockIdx.x >> 2) - 1;   // 0..nl-1
        const int nwl = nl * NWPB;
        const int gw  = lb * NWPB + wib;
        const int chunk = (NVOCAB + nwl - 1) / nwl;
        const int begin = gw * chunk;
        const int end   = (begin + chunk < NVOCAB) ? begin + chunk : NVOCAB;
        unsigned* myflag = h2f + (lb & 7) * 32;

        for (int t = 0; t < NSTEP; ++t) {
            if (tid == 0) {
                while (__hip_atomic_load(myflag, __ATOMIC_ACQUIRE, __HIP_MEMORY_SCOPE_AGENT) < (unsigned)(t + 1))
                    __builtin_amdgcn_s_sleep(4);
                __threadfence();
            }
            __syncthreads();
            for (int i = tid * 4; i < HID; i += NT * 4)
                *(float4*)(sX + i) = *(const float4*)(h2b + (size_t)t * HID + i);
            __syncthreads();

            float* orow = out + (size_t)t * NVOCAB;
            float m = NEG_BIG, s = 0.f;
            if (use16) {
                int r = begin;
                for (; r + 4 <= end; r += 4) {
                    float v0, v1, v2, v3;
                    dot4_bf16(w16 + (size_t)r * HID, sX, lane, v0, v1, v2, v3);
                    v0 += b_out[r]; v1 += b_out[r + 1]; v2 += b_out[r + 2]; v3 += b_out[r + 3];
                    if (lane == 0) { orow[r] = v0; orow[r + 1] = v1; orow[r + 2] = v2; orow[r + 3] = v3; }
                    online_upd(m, s, v0); online_upd(m, s, v1);
                    online_upd(m, s, v2); online_upd(m, s, v3);
                }
                for (; r < end; ++r) {
                    float v = dot1_bf16(w16 + (size_t)r * HID, sX, lane) + b_out[r];
                    if (lane == 0) orow[r] = v;
                    online_upd(m, s, v);
                }
            } else {
                for (int r = begin; r < end; ++r) {
                    float v = row_dotT<HID>(w_out + (size_t)r * HID, sX, lane) + b_out[r];
                    if (lane == 0) orow[r] = v;
                    online_upd(m, s, v);
                }
            }
            // block partial -> PM/PS[t][lb]
            if (lane == 0) { sRm[wib] = m; sRs[wib] = s; }
            __syncthreads();
            unsigned* lbar_t = ctrl + LBAR_W + t * 256;   // 8 sub-counters, stride 32 words
            if (tid == 0) {
                float M = sRm[0], S = sRs[0];
                for (int w = 1; w < NWPB; ++w) smax_comb(M, S, sRm[w], sRs[w]);
                PM[t * 1024 + lb] = M; PS[t * 1024 + lb] = S;
                __threadfence();
                __hip_atomic_fetch_add(lbar_t + (lb & 7) * 32, 1u,
                                       __ATOMIC_RELEASE, __HIP_MEMORY_SCOPE_AGENT);
            }
            // wave 0 polls the 8 sub-counters
            if (wib == 0) {
                while (true) {
                    unsigned v = (lane < 8)
                        ? __hip_atomic_load(lbar_t + lane * 32, __ATOMIC_ACQUIRE, __HIP_MEMORY_SCOPE_AGENT)
                        : 0u;
                    if (wave_reduce_i((int)v) >= nl) break;
                    __builtin_amdgcn_s_sleep(8);
                }
                if (lane == 0) __threadfence();
            }
            __syncthreads();
            // combined offset over all nl partials
            {
                float M = NEG_BIG, S = 0.f;
                for (int i = tid; i < nl; i += NT) smax_comb(M, S, PM[t * 1024 + i], PS[t * 1024 + i]);
#pragma unroll
                for (int o = 32; o; o >>= 1) {
                    float m2 = __shfl_xor(M, o, 64), s2 = __shfl_xor(S, o, 64);
                    smax_comb(M, S, m2, s2);
                }
                if (lane == 0) { sRm[wib] = M; sRs[wib] = S; }
                __syncthreads();
                M = sRm[0]; S = sRs[0];
                for (int w = 1; w < NWPB; ++w) smax_comb(M, S, sRm[w], sRs[w]);
                float off = M + __logf(S);
                for (int i = begin + lane; i < end; i += 64) orow[i] -= off;
            }
            __syncthreads();
        }
    }
}

extern "C" void kernel_launch(void* const* d_in, const int* in_sizes, int n_in,
                              void* d_out, int out_size, void* d_ws, size_t ws_size,
                              hipStream_t stream) {
    const float* vid   = (const float*)d_in[0];
    const float* w_ih1 = (const float*)d_in[1];
    const float* w_hh1 = (const float*)d_in[2];
    const float* b_ih1 = (const float*)d_in[3];
    const float* b_hh1 = (const float*)d_in[4];
    const float* w_ih2 = (const float*)d_in[5];
    const float* w_hh2 = (const float*)d_in[6];
    const float* b_ih2 = (const float*)d_in[7];
    const float* b_hh2 = (const float*)d_in[8];
    const float* emb   = (const float*)d_in[9];
    const float* w_out = (const float*)d_in[10];
    const float* b_out = (const float*)d_in[11];
    float* out = (float*)d_out;
    char* wsb  = (char*)d_ws;

    int use16 = (ws_size >= WS_NEED) ? 1 : 0;

    hipMemsetAsync(d_ws, 0, CTRL_BYTES, stream);

    if (use16) {
        int n = NVOCAB * HID;
        cvt_kernel<<<dim3(n / 1024), dim3(256), 0, stream>>>(
            w_out, (unsigned short*)(wsb + W16_OFF), n);
    }

    int occ = 0;
    if (hipOccupancyMaxActiveBlocksPerMultiprocessor(&occ, seq2seq_kernel, NT, 0) != hipSuccess || occ < 1)
        occ = 1;
    int nb = occ * 256;
    if (nb > 1024) nb = 1024;
    nb &= ~3;                       // multiple of 4 for the 1:3 split
    if (nb < 4) nb = 4;
    int nr = nb >> 2, nl = nb - nr;

    void* args[] = { &vid, &w_ih1, &w_hh1, &b_ih1, &b_hh1,
                     &w_ih2, &w_hh2, &b_ih2, &b_hh2,
                     &emb, &w_out, &b_out, &use16, &nr, &nl, &out, &wsb };
    hipLaunchCooperativeKernel((const void*)seq2seq_kernel,
                               dim3(nb), dim3(NT), args, 0, stream);
}